// Round 1
// baseline (235.384 us; speedup 1.0000x reference)
//
#include <hip/hip_runtime.h>
#include <hip/hip_bf16.h>

// Problem shapes (fixed):
//   hidden_states fp32 [WORLD=8][SEQ=2048][HID=4096]
//   gate_proj     fp32 [OUTD=8192][HID=4096]
//   out           fp32 [SEQ=2048][OUTD=8192]
// out = (sum_w hs[w]) @ W^T   (reduce-scatter sum commutes into the GEMM)

#define HID   4096
#define SEQ   2048
#define WORLD 8
#define OUTD  8192

typedef __bf16 bf16x8 __attribute__((ext_vector_type(8)));
typedef short  s16x8  __attribute__((ext_vector_type(8)));
typedef float  f32x4  __attribute__((ext_vector_type(4)));

typedef const __attribute__((address_space(1))) void* gas1_ptr;
typedef __attribute__((address_space(3))) void*       las3_ptr;

static __device__ __forceinline__ unsigned short f2bf(float f) {
    union { float f; unsigned u; } v; v.f = f;
    unsigned u = v.u;
    u += 0x7fffu + ((u >> 16) & 1u);   // round-to-nearest-even
    return (unsigned short)(u >> 16);
}

// ---------------- Kernel 1: reduce over world dim + cast to bf16 ----------------
__global__ void reduce_x_kernel(const float* __restrict__ hs,
                                unsigned short* __restrict__ xb) {
    const int total4 = SEQ * HID / 4;
    const float4* h4 = (const float4*)hs;
    ushort4* o4 = (ushort4*)xb;
    for (int i = blockIdx.x * blockDim.x + threadIdx.x; i < total4;
         i += gridDim.x * blockDim.x) {
        float4 s = h4[i];
        #pragma unroll
        for (int w = 1; w < WORLD; ++w) {
            float4 t = h4[i + w * total4];
            s.x += t.x; s.y += t.y; s.z += t.z; s.w += t.w;
        }
        ushort4 o;
        o.x = f2bf(s.x); o.y = f2bf(s.y); o.z = f2bf(s.z); o.w = f2bf(s.w);
        o4[i] = o;
    }
}

// ---------------- Kernel 2: cast W to bf16 ----------------
__global__ void convert_w_kernel(const float* __restrict__ w,
                                 unsigned short* __restrict__ wb) {
    const int total4 = OUTD * HID / 4;
    const float4* w4 = (const float4*)w;
    ushort4* o4 = (ushort4*)wb;
    for (int i = blockIdx.x * blockDim.x + threadIdx.x; i < total4;
         i += gridDim.x * blockDim.x) {
        float4 s = w4[i];
        ushort4 o;
        o.x = f2bf(s.x); o.y = f2bf(s.y); o.z = f2bf(s.z); o.w = f2bf(s.w);
        o4[i] = o;
    }
}

// ---------------- Kernel 3: bf16 GEMM  C[M][N] = A[M][K] * B[N][K]^T ----------------
// M=SEQ, N=OUTD, K=HID. A = Xsum bf16, B = W bf16 (both K-contiguous).
// 128x128 tile, BK=64, 4 waves (2x2), 64x64 per wave, mfma_f32_16x16x32_bf16.
// LDS tiles [128][64] bf16, XOR-swizzled: slot' = slot ^ (row & 7)
// (16B slots, 8 per row). global_load_lds writes linearly -> the global SOURCE
// address carries the inverse (== same) permutation; ds_read applies it too.

#define BM 128
#define BN 128
#define BK 64
#define KSTEPS (HID / BK)

__global__ __launch_bounds__(256, 2)
void gemm_bt_kernel(const unsigned short* __restrict__ A,
                    const unsigned short* __restrict__ B,
                    float* __restrict__ C) {
    __shared__ __align__(16) unsigned short lsA[BM * BK];
    __shared__ __align__(16) unsigned short lsB[BN * BK];

    const int tid  = threadIdx.x;
    const int lane = tid & 63;
    const int wave = tid >> 6;

    const int nbn = OUTD / BN;          // 64
    const int bm  = blockIdx.x / nbn;
    const int bn  = blockIdx.x % nbn;

    // ---- staging geometry: lane -> (subrow = lane>>3, slot = lane&7) ----
    // row = r*32 + wave*8 + subrow ; (row & 7) == subrow
    const int st_subrow = lane >> 3;
    const int st_slot   = lane & 7;
    const int scol      = (st_slot ^ st_subrow) * 8;   // pre-swizzled global col

    const unsigned short* aPtr =
        A + (long)(bm * BM + wave * 8 + st_subrow) * HID + scol;
    const unsigned short* bPtr =
        B + (long)(bn * BN + wave * 8 + st_subrow) * HID + scol;
    const int ldsWave = wave * 8 * BK;  // wave-uniform LDS element offset

    // ---- compute geometry ----
    const int wr = (wave >> 1) * 64;    // wave row origin in tile
    const int wc = (wave & 1) * 64;     // wave col origin in tile
    const int fr = lane & 15;           // fragment row/col
    const int fq = lane >> 4;           // quad 0..3
    const int axor = fr & 7;            // (row & 7) for all fragment rows

    f32x4 acc[4][4] = {};

    for (int kt = 0; kt < KSTEPS; ++kt) {
        const unsigned short* ap = aPtr + kt * BK;
        const unsigned short* bp = bPtr + kt * BK;
        #pragma unroll
        for (int r = 0; r < 4; ++r) {
            __builtin_amdgcn_global_load_lds(
                (gas1_ptr)(ap + (long)r * 32 * HID),
                (las3_ptr)(&lsA[ldsWave + r * 32 * BK]), 16, 0, 0);
            __builtin_amdgcn_global_load_lds(
                (gas1_ptr)(bp + (long)r * 32 * HID),
                (las3_ptr)(&lsB[ldsWave + r * 32 * BK]), 16, 0, 0);
        }
        __syncthreads();   // compiler drains vmcnt before barrier

        bf16x8 va[4][2], vb[4][2];
        #pragma unroll
        for (int m = 0; m < 4; ++m) {
            const int row = wr + m * 16 + fr;
            #pragma unroll
            for (int s = 0; s < 2; ++s) {
                const int kslot = s * 4 + fq;
                const int off = row * BK + ((kslot ^ axor) * 8);
                va[m][s] = __builtin_bit_cast(bf16x8, *(const s16x8*)&lsA[off]);
            }
        }
        #pragma unroll
        for (int n = 0; n < 4; ++n) {
            const int row = wc + n * 16 + fr;
            #pragma unroll
            for (int s = 0; s < 2; ++s) {
                const int kslot = s * 4 + fq;
                const int off = row * BK + ((kslot ^ axor) * 8);
                vb[n][s] = __builtin_bit_cast(bf16x8, *(const s16x8*)&lsB[off]);
            }
        }
        #pragma unroll
        for (int s = 0; s < 2; ++s)
            #pragma unroll
            for (int m = 0; m < 4; ++m)
                #pragma unroll
                for (int n = 0; n < 4; ++n)
                    acc[m][n] = __builtin_amdgcn_mfma_f32_16x16x32_bf16(
                        va[m][s], vb[n][s], acc[m][n], 0, 0, 0);

        __syncthreads();
    }

    // ---- epilogue: C/D layout col = lane&15, row = (lane>>4)*4 + j ----
    const long crow0 = (long)bm * BM + wr + fq * 4;
    const long ccol0 = (long)bn * BN + wc + fr;
    #pragma unroll
    for (int m = 0; m < 4; ++m)
        #pragma unroll
        for (int n = 0; n < 4; ++n)
            #pragma unroll
            for (int j = 0; j < 4; ++j)
                C[(crow0 + m * 16 + j) * OUTD + ccol0 + n * 16] = acc[m][n][j];
}

extern "C" void kernel_launch(void* const* d_in, const int* in_sizes, int n_in,
                              void* d_out, int out_size, void* d_ws, size_t ws_size,
                              hipStream_t stream) {
    const float* hs = (const float*)d_in[0];
    const float* w  = (const float*)d_in[1];
    float* out = (float*)d_out;

    unsigned short* xb = (unsigned short*)d_ws;              // 16 MB  [SEQ][HID] bf16
    unsigned short* wb = xb + (size_t)SEQ * HID;             // 64 MB  [OUTD][HID] bf16

    hipLaunchKernelGGL(reduce_x_kernel, dim3(2048), dim3(256), 0, stream, hs, xb);
    hipLaunchKernelGGL(convert_w_kernel, dim3(4096), dim3(256), 0, stream, w, wb);
    hipLaunchKernelGGL(gemm_bt_kernel, dim3((SEQ / BM) * (OUTD / BN)), dim3(256),
                       0, stream, xb, wb, out);
}